// Round 11
// baseline (4992.676 us; speedup 1.0000x reference)
//
#include <hip/hip_runtime.h>
#include <cstdint>
#include <cstddef>

// ---------------------------------------------------------------------------
// RLSTM: B=32, T=1024, F=256, H=256.
// Identities: a_rec = a_cur[idx]; gate chunk 4 unused (o_t = i_t); x@W is
// recurrence-free. Sentinel-fused sync (R11) + producer gate partials (R12)
// + phaseA fused as 192 producer blocks (R17) + xwL poller offload (R18)
// + producer pacing (R19) + PL[68] pad (R20: conflicts 2.67e7 -> 1.57e6).
// R21: partial u0 register hoist, sized under the 256-VGPR ceiling.
// h@U's 384 ds_read_b128/step (~4k cy on the CU's single LDS pipe) is the
// largest serial block left. R14's full hoist needed 256+ regs (pinned,
// AGPR-shuffle tax); the clean budget: VGPR_Count=132 + 24 float4 (96 regs)
// ~= 230 < 256. Each h@U thread hoists u0 for k-iters 0..23; iters 24..31
// read LDS as before. 384 -> 312 wave-instrs (-0.86k pipe cy/step).
// Per-output FMA sequence textually identical -> bit-exact (absmax 0.0).
// Everything else byte-identical to R20.
// ---------------------------------------------------------------------------

#define T_STEPS 1024
#define BSZ 32
#define FDIM 256
#define HDIM 256
#define G3W 384          // per-WG gate cols x batch (12*32) flat row
#define KWG 64           // recurrence workgroups
#define NWRK 192         // producer workgroups (blocks KWG..255)
#define HS 4             // h-cols per WG
#define JC 12            // gate cols per WG (3 chunks x HS)
#define HPAD 260         // LDS row pad
#define OMEGA 32
#define HSLICE 8192      // floats per hbank step slice (32*256)
#define LOOKAHEAD 64     // producer pacing window (rows ahead of consumer)
#define UHOIST 24        // k-iters of u0 held in regs (96 VGPR)

static const size_t AXC_BYTES = (size_t)KWG * T_STEPS * G3W * sizeof(float);      // 96 MiB
static const size_t HB_BYTES  = (size_t)(T_STEPS + 1) * HSLICE * sizeof(float);   // 32.8 MiB
static const size_t GX_BYTES  = (size_t)T_STEPS * sizeof(double);
static const size_t GP_BYTES  = (size_t)(T_STEPS + 1) * 128 * sizeof(double);     // ~1 MiB

__device__ __forceinline__ uint32_t uminv(uint32_t a, uint32_t b) {
  return a < b ? a : b;
}

// ------------------------------ Fused kernel -------------------------------
__global__ __launch_bounds__(256) void fusedK(const float* __restrict__ x,
                                              const float* __restrict__ W,
                                              const float* __restrict__ W_r,
                                              const float* __restrict__ U,
                                              const float* __restrict__ P,
                                              const float* __restrict__ B_bias,
                                              const float* __restrict__ P_r,
                                              const float* __restrict__ U_r,
                                              float* __restrict__ AXc,
                                              float* __restrict__ hbank,
                                              double* __restrict__ gx,
                                              double* __restrict__ gp) {
  const int tid = threadIdx.x;
  const int lane = tid & 63;

  // Shared decls for BOTH roles (sum ~96KB -> 1 block/CU).
  __shared__ __align__(16) float xs[BSZ][HPAD];    // producer: x row staging
  __shared__ double sred[BSZ];                     // producer: gx partials
  __shared__ __align__(16) float ULt[JC][HPAD];    // recur: U cols, k-major
  __shared__ __align__(16) float hL[BSZ][HPAD];    // recur: h_{t-1}
  __shared__ __align__(16) float PL[BSZ][68];      // recur: P rows (68: no 16-way bank conflict)
  __shared__ __align__(16) float acs[JC][36];      // recur: a_cur [jc][b]
  __shared__ __align__(16) float ars[JC][36];      // recur: a_rec
  __shared__ __align__(16) float red1[BSZ][JC];    // recur: k-upper partials
  __shared__ __align__(16) float xwL[2][96][4];    // recur: xw staging (pingpong)
  __shared__ float biasL[JC];

  // ======================= PRODUCER ROLE (blocks >= KWG) ===================
  if (blockIdx.x >= KWG) {
    const int wk = blockIdx.x - KWG;  // 0..191
    for (int t = wk; t < T_STEPS; t += NWRK) {
      // ---- pacing gate: row t waits for h-slice (t-LOOKAHEAD) to publish.
      if (t >= LOOKAHEAD) {
        if (tid == 0) {
          const uint64_t ha =
              (uint64_t)(hbank + (size_t)(t - LOOKAHEAD) * HSLICE);
          float v;
          int guard = 0;
          for (;;) {
            asm volatile("global_load_dword %0, %1, off sc0 sc1\n\t"
                         "s_waitcnt vmcnt(0)"
                         : "=&v"(v) : "v"(ha) : "memory");
            if (__float_as_uint(v) != 0xFFFFFFFFu) break;
            if (++guard > (1 << 20)) break;  // fail open, never hang
            __builtin_amdgcn_s_sleep(16);    // ~1k cy between checks
          }
        }
        __syncthreads();
      }

      for (int i = tid; i < BSZ * FDIM / 4; i += 256) {
        const int b = (i * 4) >> 8;
        const int k = (i * 4) & 255;
        *(float4*)&xs[b][k] =
            *(const float4*)&x[((size_t)b * T_STEPS + t) * FDIM + k];
      }
      __syncthreads();

      for (int pass = 0; pass < 3; ++pass) {
        const int j = pass * 256 + tid;  // gate col in [0,768)
        float acc[BSZ];
#pragma unroll
        for (int b = 0; b < BSZ; ++b) acc[b] = 0.f;
        for (int k0 = 0; k0 < FDIM; k0 += 4) {
          const float w0 = W[(size_t)(k0 + 0) * 1024 + j];
          const float w1 = W[(size_t)(k0 + 1) * 1024 + j];
          const float w2 = W[(size_t)(k0 + 2) * 1024 + j];
          const float w3 = W[(size_t)(k0 + 3) * 1024 + j];
#pragma unroll
          for (int b = 0; b < BSZ; ++b) {
            const float4 xv = *(const float4*)&xs[b][k0];  // LDS broadcast
            acc[b] = fmaf(xv.x, w0, acc[b]);
            acc[b] = fmaf(xv.y, w1, acc[b]);
            acc[b] = fmaf(xv.z, w2, acc[b]);
            acc[b] = fmaf(xv.w, w3, acc[b]);
          }
        }
        // AXc[wg][t][b*12 + slot], wg = (j%256)/4, slot = (j/256)*4 + j%4
        const int wgj = (j >> 2) & 63;
        const int slot = ((j >> 8) << 2) | (j & 3);
        float* dst = AXc + ((size_t)wgj * T_STEPS + t) * G3W + slot;
        // coherent stores: LLC-visible for the recurrence blocks' polls
#pragma unroll
        for (int b = 0; b < BSZ; ++b) {
          asm volatile("global_store_dword %0, %1, off sc0 sc1"
                       :: "v"((uint64_t)(dst + b * 12)), "v"(acc[b])
                       : "memory");
        }
      }

      if (tid < BSZ) {
        double s = 0.0;
        for (int k = 0; k < FDIM; k += 4) {
          const float4 xv = *(const float4*)&xs[tid][k];
          const float4 wv = *(const float4*)&W_r[k];
          s = fma((double)xv.x, (double)wv.x, s);
          s = fma((double)xv.y, (double)wv.y, s);
          s = fma((double)xv.z, (double)wv.z, s);
          s = fma((double)xv.w, (double)wv.w, s);
        }
        sred[tid] = s;
      }
      __syncthreads();
      if (tid == 0) {
        double g = 0.0;
        for (int b = 0; b < BSZ; ++b) g = fma((double)P_r[b], sred[b], g);
        asm volatile("global_store_dwordx2 %0, %1, off sc0 sc1"
                     :: "v"((uint64_t)(gx + t)), "v"(g)
                     : "memory");
      }
      __syncthreads();  // xs/sred safe for next row
    }
    return;
  }

  // ===================== RECURRENCE ROLE (blocks < KWG) ====================
  const int wg = blockIdx.x;

  for (int i = tid; i < JC * HDIM; i += 256) {
    const int jc = i >> 8, k = i & 255;
    const int col = (jc >> 2) * HDIM + wg * HS + (jc & 3);
    ULt[jc][k] = U[(size_t)k * 1024 + col];
  }
  for (int i = tid; i < BSZ * 64; i += 256) PL[i >> 6][i & 63] = P[i];
  if (tid < JC) biasL[tid] = B_bias[(tid >> 2) * HDIM + wg * HS + (tid & 3)];

  // owner (tid<128) gate-partial weight: P_r[b] * U_r[wg*4+hc], fp64
  double wgt = 0.0;
  if (tid < 128) {
    wgt = (double)P_r[tid >> 2] * (double)U_r[wg * HS + (tid & 3)];
  }

  // h@U map: threads 64..255, u in [0,192): khalf = u/96 (k-range),
  // r = u%96: jcp = r%6, bA = r/6; outputs (bA,bB=bA+16) x (jc0,jc1).
  const int u = (tid >= 64) ? (tid - 64) : 0;
  const int khalf = u / 96;
  const int rmap = u % 96;
  const int jcp = rmap % 6, bA = rmap / 6;
  const int jc0 = 2 * jcp, jc1 = jc0 + 1;
  const int bB = bA + 16;
  const int kb = khalf * 128;

  const int ob = tid >> 2, ohc = tid & 3;  // owner mapping (tid<128)
  const int grow = tid & 31;               // gather scatter mapping
  const int gc0 = (tid >> 5) * 4;

  float* __restrict__ AXwg = AXc + (size_t)wg * T_STEPS * G3W;

  float creg = 0.f;  // c state: threads tid<128 own (b=tid>>2, hc=tid&3)
  __syncthreads();   // staging complete

  // ---- R21: hoist u0 for k-iters 0..UHOIST-1 into regs (96 VGPR).
  // Compile-time indices + full unroll -> stays in VGPRs; 132+96 < 256
  // so no AGPR/scratch spill (R14's failure mode).
  float4 uA[UHOIST];
  if (tid >= 64) {
#pragma unroll
    for (int kk = 0; kk < UHOIST; ++kk) {
      uA[kk] = *(const float4*)&ULt[jc0][kb + 4 * kk];
    }
  }

  // xw poll (threads 160..255, one per combine thread rmap in [0,96)):
  // coherent sentinel-poll of AXc row TT, deposited into xwL[(TT)&1][rmap].
#define XW_POLL(TT)                                                            \
  if (tid >= 160) {                                                            \
    const uint64_t xa = (uint64_t)(AXwg + (size_t)(TT)*G3W + bA * JC + jc0);   \
    const uint64_t xb = (uint64_t)(AXwg + (size_t)(TT)*G3W + bB * JC + jc0);   \
    float2 pA, pB;                                                             \
    int guard = 0;                                                             \
    for (;;) {                                                                 \
      asm volatile("global_load_dwordx2 %0, %2, off sc0 sc1\n\t"               \
                   "global_load_dwordx2 %1, %3, off sc0 sc1\n\t"               \
                   "s_waitcnt vmcnt(0)"                                        \
                   : "=&v"(pA), "=&v"(pB)                                      \
                   : "v"(xa), "v"(xb)                                          \
                   : "memory");                                                \
      const int ok = (__float_as_uint(pA.x) != 0xFFFFFFFFu) &&                 \
                     (__float_as_uint(pA.y) != 0xFFFFFFFFu) &&                 \
                     (__float_as_uint(pB.x) != 0xFFFFFFFFu) &&                 \
                     (__float_as_uint(pB.y) != 0xFFFFFFFFu);                   \
      if (__all(ok)) break;                                                    \
      if (++guard > (1 << 18)) break; /* fail loud (NaN), never hang */        \
      __builtin_amdgcn_s_sleep(2);                                             \
    }                                                                          \
    xwL[(TT) & 1][rmap][0] = pA.x;                                             \
    xwL[(TT) & 1][rmap][1] = pA.y;                                             \
    xwL[(TT) & 1][rmap][2] = pB.x;                                             \
    xwL[(TT) & 1][rmap][3] = pB.y;                                             \
  }

  XW_POLL(0)  // prologue: row 0 -> buf[0] (visible after first barrier B)

  for (int t = 0; t < T_STEPS; ++t) {
    // ---- fused poll+gather of h_{t-1}: retry 8 coalesced dwordx4 bypass
    // loads until no dword holds the 0xFFFFFFFF sentinel. This IS the
    // cross-WG sync: data visibility = readiness (1 LLC hop + detect).
    {
      const uint64_t base =
          (uint64_t)(hbank + (size_t)t * HSLICE) + (uint64_t)tid * 16u;
      const uint64_t a0 = base;
      const uint64_t a1 = base + 4096u;
      const uint64_t a2 = base + 8192u;
      const uint64_t a3 = base + 12288u;
      const uint64_t a4 = base + 16384u;
      const uint64_t a5 = base + 20480u;
      const uint64_t a6 = base + 24576u;
      const uint64_t a7 = base + 28672u;
      float4 r0, r1, r2, r3, r4, r5, r6, r7;
      int guard = 0;
      for (;;) {
        asm volatile(
            "global_load_dwordx4 %0, %8, off sc0 sc1\n\t"
            "global_load_dwordx4 %1, %9, off sc0 sc1\n\t"
            "global_load_dwordx4 %2, %10, off sc0 sc1\n\t"
            "global_load_dwordx4 %3, %11, off sc0 sc1\n\t"
            "global_load_dwordx4 %4, %12, off sc0 sc1\n\t"
            "global_load_dwordx4 %5, %13, off sc0 sc1\n\t"
            "global_load_dwordx4 %6, %14, off sc0 sc1\n\t"
            "global_load_dwordx4 %7, %15, off sc0 sc1\n\t"
            "s_waitcnt vmcnt(0)"
            : "=&v"(r0), "=&v"(r1), "=&v"(r2), "=&v"(r3),
              "=&v"(r4), "=&v"(r5), "=&v"(r6), "=&v"(r7)
            : "v"(a0), "v"(a1), "v"(a2), "v"(a3),
              "v"(a4), "v"(a5), "v"(a6), "v"(a7)
            : "memory");
        // any dword == 0xFFFFFFFF  <=>  min over ~dword == 0
        uint32_t m = 0xFFFFFFFFu;
#define CHK(f) m = uminv(m, ~__float_as_uint(f))
        CHK(r0.x); CHK(r0.y); CHK(r0.z); CHK(r0.w);
        CHK(r1.x); CHK(r1.y); CHK(r1.z); CHK(r1.w);
        CHK(r2.x); CHK(r2.y); CHK(r2.z); CHK(r2.w);
        CHK(r3.x); CHK(r3.y); CHK(r3.z); CHK(r3.w);
        CHK(r4.x); CHK(r4.y); CHK(r4.z); CHK(r4.w);
        CHK(r5.x); CHK(r5.y); CHK(r5.z); CHK(r5.w);
        CHK(r6.x); CHK(r6.y); CHK(r6.z); CHK(r6.w);
        CHK(r7.x); CHK(r7.y); CHK(r7.z); CHK(r7.w);
#undef CHK
        if (m != 0u) break;               // all 32 dwords valid
        if (++guard > (1 << 16)) break;   // fail loud (NaN), never hang
        __builtin_amdgcn_s_sleep(1);      // throttle spin traffic at LLC
      }
      *(float4*)&hL[grow][gc0 + 0]   = r0;
      *(float4*)&hL[grow][gc0 + 32]  = r1;
      *(float4*)&hL[grow][gc0 + 64]  = r2;
      *(float4*)&hL[grow][gc0 + 96]  = r3;
      *(float4*)&hL[grow][gc0 + 128] = r4;
      *(float4*)&hL[grow][gc0 + 160] = r5;
      *(float4*)&hL[grow][gc0 + 192] = r6;
      *(float4*)&hL[grow][gc0 + 224] = r7;
    }
    __syncthreads();  // B: hL complete (+ xwL writes from prev step visible)

    // ---- wave 0: recall gate (gp + gx sentinel poll) + a_rec prefetch ----
    // ---- threads 64..255 (3 waves): h@U k-half, 2b x 2jc -----------------
    float s00 = 0.f, s01 = 0.f, s10 = 0.f, s11 = 0.f;
    if (tid < 64) {
      if (t >= OMEGA) {
        const uint64_t ga0 = (uint64_t)(gp + (size_t)t * 128 + lane);
        const uint64_t ga1 = ga0 + 512u;  // +64 doubles
        const uint64_t gxa = (uint64_t)(gx + t);
        double d0, d1, gxv;
        int guard = 0;
        for (;;) {
          asm volatile(
              "global_load_dwordx2 %0, %3, off sc0 sc1\n\t"
              "global_load_dwordx2 %1, %4, off sc0 sc1\n\t"
              "global_load_dwordx2 %2, %5, off sc0 sc1\n\t"
              "s_waitcnt vmcnt(0)"
              : "=&v"(d0), "=&v"(d1), "=&v"(gxv)
              : "v"(ga0), "v"(ga1), "v"(gxa)
              : "memory");
          const int ok = (__double_as_longlong(d0) != -1ll) &&
                         (__double_as_longlong(d1) != -1ll) &&
                         (__double_as_longlong(gxv) != -1ll);
          if (__all(ok)) break;
          if (++guard > (1 << 16)) break;  // fail loud, never hang
          __builtin_amdgcn_s_sleep(1);
        }
        double v = d0 + d1;
        v += __shfl_xor(v, 32, 64);
        v += __shfl_xor(v, 16, 64);
        v += __shfl_xor(v, 8, 64);
        v += __shfl_xor(v, 4, 64);
        v += __shfl_xor(v, 2, 64);
        v += __shfl_xor(v, 1, 64);
        int idx = 0;
        if (tid == 0) {
          const double g = gxv + v;
          const double gate = 1.0 / (1.0 + exp(-g));
          idx = (int)rint((double)t * gate);  // ties-to-even == jnp.round
          if (idx > t - 1) idx = t - 1;
          if (idx < 0) idx = 0;
        }
        idx = __shfl(idx, 0, 64);
        // a_rec = a_cur[idx]: contiguous 1.5KB block in our own AXc region
        const float* __restrict__ src = AXwg + (size_t)idx * G3W;
        float av[6];
#pragma unroll
        for (int j = 0; j < 6; ++j) av[j] = src[lane + j * 64];
#pragma unroll
        for (int j = 0; j < 6; ++j) {
          const int f = lane + j * 64;
          ars[f % JC][f / JC] = av[j];
        }
      }
    } else {
      // iters 0..UHOIST-1: u0 from regs (3 LDS reads/iter). Same values,
      // same per-output FMA order -> bit-exact.
#pragma unroll
      for (int kk = 0; kk < UHOIST; ++kk) {
        const int k = kb + 4 * kk;
        const float4 u0 = uA[kk];
        const float4 u1 = *(const float4*)&ULt[jc1][k];
        const float4 h0 = *(const float4*)&hL[bA][k];
        const float4 h1 = *(const float4*)&hL[bB][k];
        s00 = fmaf(h0.x, u0.x, s00); s00 = fmaf(h0.y, u0.y, s00);
        s00 = fmaf(h0.z, u0.z, s00); s00 = fmaf(h0.w, u0.w, s00);
        s01 = fmaf(h0.x, u1.x, s01); s01 = fmaf(h0.y, u1.y, s01);
        s01 = fmaf(h0.z, u1.z, s01); s01 = fmaf(h0.w, u1.w, s01);
        s10 = fmaf(h1.x, u0.x, s10); s10 = fmaf(h1.y, u0.y, s10);
        s10 = fmaf(h1.z, u0.z, s10); s10 = fmaf(h1.w, u0.w, s10);
        s11 = fmaf(h1.x, u1.x, s11); s11 = fmaf(h1.y, u1.y, s11);
        s11 = fmaf(h1.z, u1.z, s11); s11 = fmaf(h1.w, u1.w, s11);
      }
      // iters UHOIST..31: both U cols from LDS (as before)
      for (int k = kb + 4 * UHOIST; k < kb + 128; k += 4) {
        const float4 u0 = *(const float4*)&ULt[jc0][k];
        const float4 u1 = *(const float4*)&ULt[jc1][k];
        const float4 h0 = *(const float4*)&hL[bA][k];
        const float4 h1 = *(const float4*)&hL[bB][k];
        s00 = fmaf(h0.x, u0.x, s00); s00 = fmaf(h0.y, u0.y, s00);
        s00 = fmaf(h0.z, u0.z, s00); s00 = fmaf(h0.w, u0.w, s00);
        s01 = fmaf(h0.x, u1.x, s01); s01 = fmaf(h0.y, u1.y, s01);
        s01 = fmaf(h0.z, u1.z, s01); s01 = fmaf(h0.w, u1.w, s01);
        s10 = fmaf(h1.x, u0.x, s10); s10 = fmaf(h1.y, u0.y, s10);
        s10 = fmaf(h1.z, u0.z, s10); s10 = fmaf(h1.w, u0.w, s10);
        s11 = fmaf(h1.x, u1.x, s11); s11 = fmaf(h1.y, u1.y, s11);
        s11 = fmaf(h1.z, u1.z, s11); s11 = fmaf(h1.w, u1.w, s11);
      }
      if (khalf == 1) {  // store k-upper partials
        *(float2*)&red1[bA][jc0] = make_float2(s00, s01);
        *(float2*)&red1[bB][jc0] = make_float2(s10, s11);
      }
    }
    __syncthreads();  // C1: red1 + ars complete

    // ---- combine (khalf0 threads): a_cur = s_low + red1 + xw (R1 assoc) --
    if (tid >= 64 && tid < 160) {
      const size_t aA = (size_t)t * G3W + bA * JC + jc0;
      const size_t aB = (size_t)t * G3W + bB * JC + jc0;
      const float4 xw = *(const float4*)&xwL[t & 1][rmap][0];
      const float2 rA = *(const float2*)&red1[bA][jc0];
      const float2 rB = *(const float2*)&red1[bB][jc0];
      const float v00 = s00 + rA.x + xw.x;
      const float v01 = s01 + rA.y + xw.y;
      const float v10 = s10 + rB.x + xw.z;
      const float v11 = s11 + rB.y + xw.w;
      *(float2*)&AXwg[aA] = make_float2(v00, v01);  // bank for future a_rec
      *(float2*)&AXwg[aB] = make_float2(v10, v11);
      acs[jc0][bA] = v00;  acs[jc1][bA] = v01;
      acs[jc0][bB] = v10;  acs[jc1][bB] = v11;
      if (t < OMEGA) {  // use_self: a_rec == a_cur
        ars[jc0][bA] = v00;  ars[jc1][bA] = v01;
        ars[jc0][bB] = v10;  ars[jc1][bB] = v11;
      }
    }
    __syncthreads();  // C2: acs/ars complete

    // ---- owners: gates = P @ [a_cur; a_rec] + bias, LSTM, direct publish -
    if (tid < BSZ * HS) {
      float gi = biasL[ohc];
      float gf = biasL[4 + ohc];
      float gg = biasL[8 + ohc];
#pragma unroll
      for (int b4 = 0; b4 < BSZ; b4 += 4) {
        const float4 pv = *(const float4*)&PL[ob][b4];
        const float4 ai = *(const float4*)&acs[ohc][b4];
        const float4 af = *(const float4*)&acs[4 + ohc][b4];
        const float4 ag = *(const float4*)&acs[8 + ohc][b4];
        gi = fmaf(pv.x, ai.x, gi); gi = fmaf(pv.y, ai.y, gi);
        gi = fmaf(pv.z, ai.z, gi); gi = fmaf(pv.w, ai.w, gi);
        gf = fmaf(pv.x, af.x, gf); gf = fmaf(pv.y, af.y, gf);
        gf = fmaf(pv.z, af.z, gf); gf = fmaf(pv.w, af.w, gf);
        gg = fmaf(pv.x, ag.x, gg); gg = fmaf(pv.y, ag.y, gg);
        gg = fmaf(pv.z, ag.z, gg); gg = fmaf(pv.w, ag.w, gg);
      }
#pragma unroll
      for (int b4 = 0; b4 < BSZ; b4 += 4) {
        const float4 pv = *(const float4*)&PL[ob][BSZ + b4];
        const float4 ai = *(const float4*)&ars[ohc][b4];
        const float4 af = *(const float4*)&ars[4 + ohc][b4];
        const float4 ag = *(const float4*)&ars[8 + ohc][b4];
        gi = fmaf(pv.x, ai.x, gi); gi = fmaf(pv.y, ai.y, gi);
        gi = fmaf(pv.z, ai.z, gi); gi = fmaf(pv.w, ai.w, gi);
        gf = fmaf(pv.x, af.x, gf); gf = fmaf(pv.y, af.y, gf);
        gf = fmaf(pv.z, af.z, gf); gf = fmaf(pv.w, af.w, gf);
        gg = fmaf(pv.x, ag.x, gg); gg = fmaf(pv.y, ag.y, gg);
        gg = fmaf(pv.z, ag.z, gg); gg = fmaf(pv.w, ag.w, gg);
      }
      const float iv = 1.f / (1.f + expf(-gi));
      const float fv = 1.f / (1.f + expf(-gf));
      const float gv = tanhf(gg);
      creg = fmaf(fv, creg, iv * gv);
      const float hv = iv * tanhf(creg);  // o_t = i_t (faithful to source)
      // direct publish: [wg][b][c] flat idx == tid (b=tid>>2, hc=tid&3).
      // NO drain: pre-store memory is sentinel, early readers just retry.
      const uint64_t daddr =
          (uint64_t)(hbank + (size_t)(t + 1) * HSLICE + (size_t)wg * (BSZ * HS)) +
          (uint64_t)tid * 4u;
      asm volatile("global_store_dword %0, %1, off sc0 sc1"
                   :: "v"(daddr), "v"(hv)
                   : "memory");
      // recall-gate partial for step t+1: per owner wave, fixed butterfly.
      double p = wgt * (double)hv;
      p += __shfl_xor(p, 32, 64);
      p += __shfl_xor(p, 16, 64);
      p += __shfl_xor(p, 8, 64);
      p += __shfl_xor(p, 4, 64);
      p += __shfl_xor(p, 2, 64);
      p += __shfl_xor(p, 1, 64);
      if (lane == 0) {
        const uint64_t pa =
            (uint64_t)(gp + (size_t)(t + 1) * 128 + (size_t)((tid >> 6) * 64 + wg));
        asm volatile("global_store_dwordx2 %0, %1, off sc0 sc1"
                     :: "v"(pa), "v"(p)
                     : "memory");
      }
    }
    // ---- threads 160..255 (idle since C1-store): poll xw for t+1 into the
    // other xwL buffer. Overlaps owners' P-mix; loop-top B orders visibility.
    if (t + 1 < T_STEPS) { XW_POLL(t + 1) }
    // no barrier D: next step's poll-gather IS the sync
  }
#undef XW_POLL
}

// ------------------------------ Output -------------------------------------
__global__ void outK(const float* __restrict__ hbank, const float* __restrict__ W_out,
                     const float* __restrict__ b_out, float* __restrict__ out) {
  const int b = threadIdx.x;
  if (b < BSZ) {
    const float* h = hbank + (size_t)T_STEPS * HSLICE;  // [wg][b][c]
    float s = 0.f;
    for (int wg = 0; wg < KWG; ++wg) {
      const float4 hv = *(const float4*)&h[wg * (BSZ * HS) + b * HS];
      const float4 wv = *(const float4*)&W_out[wg * HS];
      s = fmaf(hv.x, wv.x, s); s = fmaf(hv.y, wv.y, s);
      s = fmaf(hv.z, wv.z, s); s = fmaf(hv.w, wv.w, s);
    }
    out[b] = s + b_out[0];
  }
}

// ------------------------------ Launch -------------------------------------
extern "C" void kernel_launch(void* const* d_in, const int* in_sizes, int n_in,
                              void* d_out, int out_size, void* d_ws, size_t ws_size,
                              hipStream_t stream) {
  const float* x      = (const float*)d_in[0];
  const float* W      = (const float*)d_in[1];
  const float* U      = (const float*)d_in[2];
  const float* P      = (const float*)d_in[3];
  const float* B_bias = (const float*)d_in[4];
  const float* W_r    = (const float*)d_in[5];
  const float* P_r    = (const float*)d_in[6];
  const float* U_r    = (const float*)d_in[7];
  const float* W_out  = (const float*)d_in[8];
  const float* b_out  = (const float*)d_in[9];

  char* ws = (char*)d_ws;
  float*    AXc   = (float*)ws;
  float*    hbank = (float*)(ws + AXC_BYTES);
  double*   gx    = (double*)(ws + AXC_BYTES + HB_BYTES);
  double*   gp    = (double*)(ws + AXC_BYTES + HB_BYTES + GX_BYTES);

  // Sentinel prefill (0xFF bytes -> all-ones dwords/qwords: never produced
  // by finite arithmetic): AXc + gx sentinel'd for producer/consumer
  // pipelining, then h0 = 0 in hbank slice 0.
  hipMemsetAsync(AXc, 0xFF, AXC_BYTES, stream);
  hipMemsetAsync(hbank, 0xFF, HB_BYTES, stream);
  hipMemsetAsync(gx, 0xFF, GX_BYTES, stream);
  hipMemsetAsync(gp, 0xFF, GP_BYTES, stream);
  hipMemsetAsync(hbank, 0, (size_t)HSLICE * sizeof(float), stream);

  fusedK<<<KWG + NWRK, 256, 0, stream>>>(x, W, W_r, U, P, B_bias, P_r, U_r,
                                         AXc, hbank, gx, gp);
  outK<<<1, 64, 0, stream>>>(hbank, W_out, b_out, (float*)d_out);
}

// Round 12
// 4775.291 us; speedup vs baseline: 1.0455x; 1.0455x over previous
//
#include <hip/hip_runtime.h>
#include <cstdint>
#include <cstddef>

// ---------------------------------------------------------------------------
// RLSTM: B=32, T=1024, F=256, H=256.
// Identities: a_rec = a_cur[idx]; gate chunk 4 unused (o_t = i_t); x@W is
// recurrence-free. Sentinel-fused sync (R11) + producer gate partials (R12)
// + phaseA fused as 192 producer blocks (R17) + xwL poller offload (R18)
// + producer pacing (R19) + PL[68] pad (R20: conflicts 2.67e7 -> 1.57e6).
// R22 = EXACT R20 REVERT. R21's partial u0 hoist (clean, VGPR 204, no
// spill) regressed +210us with conflicts exploding 26x (1.57e6 -> 4.09e7):
// thinning the h@U LDS stream perturbs the compiler's bank phasing and
// loses more than the removed instructions gain. Closed lever (3rd probe:
// R14 full hoist, R16 union hoist, R21 partial hoist -- all negative).
// R20 is the best measured configuration: total 4786.7us, fusedK 4731,
// step 4.62us. Remaining cycles: mandatory cross-WG coherence RT +
// straggler fan-in (~1.5-2k cy, R12/R15-probed), h@U LDS block (~4k cy,
// unthinnable), order-pinned combine/P-mix + 3 barriers (~2k cy).
// ---------------------------------------------------------------------------

#define T_STEPS 1024
#define BSZ 32
#define FDIM 256
#define HDIM 256
#define G3W 384          // per-WG gate cols x batch (12*32) flat row
#define KWG 64           // recurrence workgroups
#define NWRK 192         // producer workgroups (blocks KWG..255)
#define HS 4             // h-cols per WG
#define JC 12            // gate cols per WG (3 chunks x HS)
#define HPAD 260         // LDS row pad
#define OMEGA 32
#define HSLICE 8192      // floats per hbank step slice (32*256)
#define LOOKAHEAD 64     // producer pacing window (rows ahead of consumer)

static const size_t AXC_BYTES = (size_t)KWG * T_STEPS * G3W * sizeof(float);      // 96 MiB
static const size_t HB_BYTES  = (size_t)(T_STEPS + 1) * HSLICE * sizeof(float);   // 32.8 MiB
static const size_t GX_BYTES  = (size_t)T_STEPS * sizeof(double);
static const size_t GP_BYTES  = (size_t)(T_STEPS + 1) * 128 * sizeof(double);     // ~1 MiB

__device__ __forceinline__ uint32_t uminv(uint32_t a, uint32_t b) {
  return a < b ? a : b;
}

// ------------------------------ Fused kernel -------------------------------
__global__ __launch_bounds__(256) void fusedK(const float* __restrict__ x,
                                              const float* __restrict__ W,
                                              const float* __restrict__ W_r,
                                              const float* __restrict__ U,
                                              const float* __restrict__ P,
                                              const float* __restrict__ B_bias,
                                              const float* __restrict__ P_r,
                                              const float* __restrict__ U_r,
                                              float* __restrict__ AXc,
                                              float* __restrict__ hbank,
                                              double* __restrict__ gx,
                                              double* __restrict__ gp) {
  const int tid = threadIdx.x;
  const int lane = tid & 63;

  // Shared decls for BOTH roles (sum ~96KB -> 1 block/CU).
  __shared__ __align__(16) float xs[BSZ][HPAD];    // producer: x row staging
  __shared__ double sred[BSZ];                     // producer: gx partials
  __shared__ __align__(16) float ULt[JC][HPAD];    // recur: U cols, k-major
  __shared__ __align__(16) float hL[BSZ][HPAD];    // recur: h_{t-1}
  __shared__ __align__(16) float PL[BSZ][68];      // recur: P rows (68: no 16-way bank conflict)
  __shared__ __align__(16) float acs[JC][36];      // recur: a_cur [jc][b]
  __shared__ __align__(16) float ars[JC][36];      // recur: a_rec
  __shared__ __align__(16) float red1[BSZ][JC];    // recur: k-upper partials
  __shared__ __align__(16) float xwL[2][96][4];    // recur: xw staging (pingpong)
  __shared__ float biasL[JC];

  // ======================= PRODUCER ROLE (blocks >= KWG) ===================
  if (blockIdx.x >= KWG) {
    const int wk = blockIdx.x - KWG;  // 0..191
    for (int t = wk; t < T_STEPS; t += NWRK) {
      // ---- pacing gate: row t waits for h-slice (t-LOOKAHEAD) to publish.
      if (t >= LOOKAHEAD) {
        if (tid == 0) {
          const uint64_t ha =
              (uint64_t)(hbank + (size_t)(t - LOOKAHEAD) * HSLICE);
          float v;
          int guard = 0;
          for (;;) {
            asm volatile("global_load_dword %0, %1, off sc0 sc1\n\t"
                         "s_waitcnt vmcnt(0)"
                         : "=&v"(v) : "v"(ha) : "memory");
            if (__float_as_uint(v) != 0xFFFFFFFFu) break;
            if (++guard > (1 << 20)) break;  // fail open, never hang
            __builtin_amdgcn_s_sleep(16);    // ~1k cy between checks
          }
        }
        __syncthreads();
      }

      for (int i = tid; i < BSZ * FDIM / 4; i += 256) {
        const int b = (i * 4) >> 8;
        const int k = (i * 4) & 255;
        *(float4*)&xs[b][k] =
            *(const float4*)&x[((size_t)b * T_STEPS + t) * FDIM + k];
      }
      __syncthreads();

      for (int pass = 0; pass < 3; ++pass) {
        const int j = pass * 256 + tid;  // gate col in [0,768)
        float acc[BSZ];
#pragma unroll
        for (int b = 0; b < BSZ; ++b) acc[b] = 0.f;
        for (int k0 = 0; k0 < FDIM; k0 += 4) {
          const float w0 = W[(size_t)(k0 + 0) * 1024 + j];
          const float w1 = W[(size_t)(k0 + 1) * 1024 + j];
          const float w2 = W[(size_t)(k0 + 2) * 1024 + j];
          const float w3 = W[(size_t)(k0 + 3) * 1024 + j];
#pragma unroll
          for (int b = 0; b < BSZ; ++b) {
            const float4 xv = *(const float4*)&xs[b][k0];  // LDS broadcast
            acc[b] = fmaf(xv.x, w0, acc[b]);
            acc[b] = fmaf(xv.y, w1, acc[b]);
            acc[b] = fmaf(xv.z, w2, acc[b]);
            acc[b] = fmaf(xv.w, w3, acc[b]);
          }
        }
        // AXc[wg][t][b*12 + slot], wg = (j%256)/4, slot = (j/256)*4 + j%4
        const int wgj = (j >> 2) & 63;
        const int slot = ((j >> 8) << 2) | (j & 3);
        float* dst = AXc + ((size_t)wgj * T_STEPS + t) * G3W + slot;
        // coherent stores: LLC-visible for the recurrence blocks' polls
#pragma unroll
        for (int b = 0; b < BSZ; ++b) {
          asm volatile("global_store_dword %0, %1, off sc0 sc1"
                       :: "v"((uint64_t)(dst + b * 12)), "v"(acc[b])
                       : "memory");
        }
      }

      if (tid < BSZ) {
        double s = 0.0;
        for (int k = 0; k < FDIM; k += 4) {
          const float4 xv = *(const float4*)&xs[tid][k];
          const float4 wv = *(const float4*)&W_r[k];
          s = fma((double)xv.x, (double)wv.x, s);
          s = fma((double)xv.y, (double)wv.y, s);
          s = fma((double)xv.z, (double)wv.z, s);
          s = fma((double)xv.w, (double)wv.w, s);
        }
        sred[tid] = s;
      }
      __syncthreads();
      if (tid == 0) {
        double g = 0.0;
        for (int b = 0; b < BSZ; ++b) g = fma((double)P_r[b], sred[b], g);
        asm volatile("global_store_dwordx2 %0, %1, off sc0 sc1"
                     :: "v"((uint64_t)(gx + t)), "v"(g)
                     : "memory");
      }
      __syncthreads();  // xs/sred safe for next row
    }
    return;
  }

  // ===================== RECURRENCE ROLE (blocks < KWG) ====================
  const int wg = blockIdx.x;

  for (int i = tid; i < JC * HDIM; i += 256) {
    const int jc = i >> 8, k = i & 255;
    const int col = (jc >> 2) * HDIM + wg * HS + (jc & 3);
    ULt[jc][k] = U[(size_t)k * 1024 + col];
  }
  for (int i = tid; i < BSZ * 64; i += 256) PL[i >> 6][i & 63] = P[i];
  if (tid < JC) biasL[tid] = B_bias[(tid >> 2) * HDIM + wg * HS + (tid & 3)];

  // owner (tid<128) gate-partial weight: P_r[b] * U_r[wg*4+hc], fp64
  double wgt = 0.0;
  if (tid < 128) {
    wgt = (double)P_r[tid >> 2] * (double)U_r[wg * HS + (tid & 3)];
  }

  // h@U map: threads 64..255, u in [0,192): khalf = u/96 (k-range),
  // r = u%96: jcp = r%6, bA = r/6; outputs (bA,bB=bA+16) x (jc0,jc1).
  const int u = (tid >= 64) ? (tid - 64) : 0;
  const int khalf = u / 96;
  const int rmap = u % 96;
  const int jcp = rmap % 6, bA = rmap / 6;
  const int jc0 = 2 * jcp, jc1 = jc0 + 1;
  const int bB = bA + 16;
  const int kb = khalf * 128;

  const int ob = tid >> 2, ohc = tid & 3;  // owner mapping (tid<128)
  const int grow = tid & 31;               // gather scatter mapping
  const int gc0 = (tid >> 5) * 4;

  float* __restrict__ AXwg = AXc + (size_t)wg * T_STEPS * G3W;

  float creg = 0.f;  // c state: threads tid<128 own (b=tid>>2, hc=tid&3)
  __syncthreads();

  // xw poll (threads 160..255, one per combine thread rmap in [0,96)):
  // coherent sentinel-poll of AXc row TT, deposited into xwL[(TT)&1][rmap].
#define XW_POLL(TT)                                                            \
  if (tid >= 160) {                                                            \
    const uint64_t xa = (uint64_t)(AXwg + (size_t)(TT)*G3W + bA * JC + jc0);   \
    const uint64_t xb = (uint64_t)(AXwg + (size_t)(TT)*G3W + bB * JC + jc0);   \
    float2 pA, pB;                                                             \
    int guard = 0;                                                             \
    for (;;) {                                                                 \
      asm volatile("global_load_dwordx2 %0, %2, off sc0 sc1\n\t"               \
                   "global_load_dwordx2 %1, %3, off sc0 sc1\n\t"               \
                   "s_waitcnt vmcnt(0)"                                        \
                   : "=&v"(pA), "=&v"(pB)                                      \
                   : "v"(xa), "v"(xb)                                          \
                   : "memory");                                                \
      const int ok = (__float_as_uint(pA.x) != 0xFFFFFFFFu) &&                 \
                     (__float_as_uint(pA.y) != 0xFFFFFFFFu) &&                 \
                     (__float_as_uint(pB.x) != 0xFFFFFFFFu) &&                 \
                     (__float_as_uint(pB.y) != 0xFFFFFFFFu);                   \
      if (__all(ok)) break;                                                    \
      if (++guard > (1 << 18)) break; /* fail loud (NaN), never hang */        \
      __builtin_amdgcn_s_sleep(2);                                             \
    }                                                                          \
    xwL[(TT) & 1][rmap][0] = pA.x;                                             \
    xwL[(TT) & 1][rmap][1] = pA.y;                                             \
    xwL[(TT) & 1][rmap][2] = pB.x;                                             \
    xwL[(TT) & 1][rmap][3] = pB.y;                                             \
  }

  XW_POLL(0)  // prologue: row 0 -> buf[0] (visible after first barrier B)

  for (int t = 0; t < T_STEPS; ++t) {
    // ---- fused poll+gather of h_{t-1}: retry 8 coalesced dwordx4 bypass
    // loads until no dword holds the 0xFFFFFFFF sentinel. This IS the
    // cross-WG sync: data visibility = readiness (1 LLC hop + detect).
    {
      const uint64_t base =
          (uint64_t)(hbank + (size_t)t * HSLICE) + (uint64_t)tid * 16u;
      const uint64_t a0 = base;
      const uint64_t a1 = base + 4096u;
      const uint64_t a2 = base + 8192u;
      const uint64_t a3 = base + 12288u;
      const uint64_t a4 = base + 16384u;
      const uint64_t a5 = base + 20480u;
      const uint64_t a6 = base + 24576u;
      const uint64_t a7 = base + 28672u;
      float4 r0, r1, r2, r3, r4, r5, r6, r7;
      int guard = 0;
      for (;;) {
        asm volatile(
            "global_load_dwordx4 %0, %8, off sc0 sc1\n\t"
            "global_load_dwordx4 %1, %9, off sc0 sc1\n\t"
            "global_load_dwordx4 %2, %10, off sc0 sc1\n\t"
            "global_load_dwordx4 %3, %11, off sc0 sc1\n\t"
            "global_load_dwordx4 %4, %12, off sc0 sc1\n\t"
            "global_load_dwordx4 %5, %13, off sc0 sc1\n\t"
            "global_load_dwordx4 %6, %14, off sc0 sc1\n\t"
            "global_load_dwordx4 %7, %15, off sc0 sc1\n\t"
            "s_waitcnt vmcnt(0)"
            : "=&v"(r0), "=&v"(r1), "=&v"(r2), "=&v"(r3),
              "=&v"(r4), "=&v"(r5), "=&v"(r6), "=&v"(r7)
            : "v"(a0), "v"(a1), "v"(a2), "v"(a3),
              "v"(a4), "v"(a5), "v"(a6), "v"(a7)
            : "memory");
        // any dword == 0xFFFFFFFF  <=>  min over ~dword == 0
        uint32_t m = 0xFFFFFFFFu;
#define CHK(f) m = uminv(m, ~__float_as_uint(f))
        CHK(r0.x); CHK(r0.y); CHK(r0.z); CHK(r0.w);
        CHK(r1.x); CHK(r1.y); CHK(r1.z); CHK(r1.w);
        CHK(r2.x); CHK(r2.y); CHK(r2.z); CHK(r2.w);
        CHK(r3.x); CHK(r3.y); CHK(r3.z); CHK(r3.w);
        CHK(r4.x); CHK(r4.y); CHK(r4.z); CHK(r4.w);
        CHK(r5.x); CHK(r5.y); CHK(r5.z); CHK(r5.w);
        CHK(r6.x); CHK(r6.y); CHK(r6.z); CHK(r6.w);
        CHK(r7.x); CHK(r7.y); CHK(r7.z); CHK(r7.w);
#undef CHK
        if (m != 0u) break;               // all 32 dwords valid
        if (++guard > (1 << 16)) break;   // fail loud (NaN), never hang
        __builtin_amdgcn_s_sleep(1);      // throttle spin traffic at LLC
      }
      *(float4*)&hL[grow][gc0 + 0]   = r0;
      *(float4*)&hL[grow][gc0 + 32]  = r1;
      *(float4*)&hL[grow][gc0 + 64]  = r2;
      *(float4*)&hL[grow][gc0 + 96]  = r3;
      *(float4*)&hL[grow][gc0 + 128] = r4;
      *(float4*)&hL[grow][gc0 + 160] = r5;
      *(float4*)&hL[grow][gc0 + 192] = r6;
      *(float4*)&hL[grow][gc0 + 224] = r7;
    }
    __syncthreads();  // B: hL complete (+ xwL writes from prev step visible)

    // ---- wave 0: recall gate (gp + gx sentinel poll) + a_rec prefetch ----
    // ---- threads 64..255 (3 waves): h@U k-half, 2b x 2jc -----------------
    float s00 = 0.f, s01 = 0.f, s10 = 0.f, s11 = 0.f;
    if (tid < 64) {
      if (t >= OMEGA) {
        const uint64_t ga0 = (uint64_t)(gp + (size_t)t * 128 + lane);
        const uint64_t ga1 = ga0 + 512u;  // +64 doubles
        const uint64_t gxa = (uint64_t)(gx + t);
        double d0, d1, gxv;
        int guard = 0;
        for (;;) {
          asm volatile(
              "global_load_dwordx2 %0, %3, off sc0 sc1\n\t"
              "global_load_dwordx2 %1, %4, off sc0 sc1\n\t"
              "global_load_dwordx2 %2, %5, off sc0 sc1\n\t"
              "s_waitcnt vmcnt(0)"
              : "=&v"(d0), "=&v"(d1), "=&v"(gxv)
              : "v"(ga0), "v"(ga1), "v"(gxa)
              : "memory");
          const int ok = (__double_as_longlong(d0) != -1ll) &&
                         (__double_as_longlong(d1) != -1ll) &&
                         (__double_as_longlong(gxv) != -1ll);
          if (__all(ok)) break;
          if (++guard > (1 << 16)) break;  // fail loud, never hang
          __builtin_amdgcn_s_sleep(1);
        }
        double v = d0 + d1;
        v += __shfl_xor(v, 32, 64);
        v += __shfl_xor(v, 16, 64);
        v += __shfl_xor(v, 8, 64);
        v += __shfl_xor(v, 4, 64);
        v += __shfl_xor(v, 2, 64);
        v += __shfl_xor(v, 1, 64);
        int idx = 0;
        if (tid == 0) {
          const double g = gxv + v;
          const double gate = 1.0 / (1.0 + exp(-g));
          idx = (int)rint((double)t * gate);  // ties-to-even == jnp.round
          if (idx > t - 1) idx = t - 1;
          if (idx < 0) idx = 0;
        }
        idx = __shfl(idx, 0, 64);
        // a_rec = a_cur[idx]: contiguous 1.5KB block in our own AXc region
        const float* __restrict__ src = AXwg + (size_t)idx * G3W;
        float av[6];
#pragma unroll
        for (int j = 0; j < 6; ++j) av[j] = src[lane + j * 64];
#pragma unroll
        for (int j = 0; j < 6; ++j) {
          const int f = lane + j * 64;
          ars[f % JC][f / JC] = av[j];
        }
      }
    } else {
      for (int k = kb; k < kb + 128; k += 4) {
        const float4 u0 = *(const float4*)&ULt[jc0][k];
        const float4 u1 = *(const float4*)&ULt[jc1][k];
        const float4 h0 = *(const float4*)&hL[bA][k];
        const float4 h1 = *(const float4*)&hL[bB][k];
        s00 = fmaf(h0.x, u0.x, s00); s00 = fmaf(h0.y, u0.y, s00);
        s00 = fmaf(h0.z, u0.z, s00); s00 = fmaf(h0.w, u0.w, s00);
        s01 = fmaf(h0.x, u1.x, s01); s01 = fmaf(h0.y, u1.y, s01);
        s01 = fmaf(h0.z, u1.z, s01); s01 = fmaf(h0.w, u1.w, s01);
        s10 = fmaf(h1.x, u0.x, s10); s10 = fmaf(h1.y, u0.y, s10);
        s10 = fmaf(h1.z, u0.z, s10); s10 = fmaf(h1.w, u0.w, s10);
        s11 = fmaf(h1.x, u1.x, s11); s11 = fmaf(h1.y, u1.y, s11);
        s11 = fmaf(h1.z, u1.z, s11); s11 = fmaf(h1.w, u1.w, s11);
      }
      if (khalf == 1) {  // store k-upper partials
        *(float2*)&red1[bA][jc0] = make_float2(s00, s01);
        *(float2*)&red1[bB][jc0] = make_float2(s10, s11);
      }
    }
    __syncthreads();  // C1: red1 + ars complete

    // ---- combine (khalf0 threads): a_cur = s_low + red1 + xw (R1 assoc) --
    if (tid >= 64 && tid < 160) {
      const size_t aA = (size_t)t * G3W + bA * JC + jc0;
      const size_t aB = (size_t)t * G3W + bB * JC + jc0;
      const float4 xw = *(const float4*)&xwL[t & 1][rmap][0];
      const float2 rA = *(const float2*)&red1[bA][jc0];
      const float2 rB = *(const float2*)&red1[bB][jc0];
      const float v00 = s00 + rA.x + xw.x;
      const float v01 = s01 + rA.y + xw.y;
      const float v10 = s10 + rB.x + xw.z;
      const float v11 = s11 + rB.y + xw.w;
      *(float2*)&AXwg[aA] = make_float2(v00, v01);  // bank for future a_rec
      *(float2*)&AXwg[aB] = make_float2(v10, v11);
      acs[jc0][bA] = v00;  acs[jc1][bA] = v01;
      acs[jc0][bB] = v10;  acs[jc1][bB] = v11;
      if (t < OMEGA) {  // use_self: a_rec == a_cur
        ars[jc0][bA] = v00;  ars[jc1][bA] = v01;
        ars[jc0][bB] = v10;  ars[jc1][bB] = v11;
      }
    }
    __syncthreads();  // C2: acs/ars complete

    // ---- owners: gates = P @ [a_cur; a_rec] + bias, LSTM, direct publish -
    if (tid < BSZ * HS) {
      float gi = biasL[ohc];
      float gf = biasL[4 + ohc];
      float gg = biasL[8 + ohc];
#pragma unroll
      for (int b4 = 0; b4 < BSZ; b4 += 4) {
        const float4 pv = *(const float4*)&PL[ob][b4];
        const float4 ai = *(const float4*)&acs[ohc][b4];
        const float4 af = *(const float4*)&acs[4 + ohc][b4];
        const float4 ag = *(const float4*)&acs[8 + ohc][b4];
        gi = fmaf(pv.x, ai.x, gi); gi = fmaf(pv.y, ai.y, gi);
        gi = fmaf(pv.z, ai.z, gi); gi = fmaf(pv.w, ai.w, gi);
        gf = fmaf(pv.x, af.x, gf); gf = fmaf(pv.y, af.y, gf);
        gf = fmaf(pv.z, af.z, gf); gf = fmaf(pv.w, af.w, gf);
        gg = fmaf(pv.x, ag.x, gg); gg = fmaf(pv.y, ag.y, gg);
        gg = fmaf(pv.z, ag.z, gg); gg = fmaf(pv.w, ag.w, gg);
      }
#pragma unroll
      for (int b4 = 0; b4 < BSZ; b4 += 4) {
        const float4 pv = *(const float4*)&PL[ob][BSZ + b4];
        const float4 ai = *(const float4*)&ars[ohc][b4];
        const float4 af = *(const float4*)&ars[4 + ohc][b4];
        const float4 ag = *(const float4*)&ars[8 + ohc][b4];
        gi = fmaf(pv.x, ai.x, gi); gi = fmaf(pv.y, ai.y, gi);
        gi = fmaf(pv.z, ai.z, gi); gi = fmaf(pv.w, ai.w, gi);
        gf = fmaf(pv.x, af.x, gf); gf = fmaf(pv.y, af.y, gf);
        gf = fmaf(pv.z, af.z, gf); gf = fmaf(pv.w, af.w, gf);
        gg = fmaf(pv.x, ag.x, gg); gg = fmaf(pv.y, ag.y, gg);
        gg = fmaf(pv.z, ag.z, gg); gg = fmaf(pv.w, ag.w, gg);
      }
      const float iv = 1.f / (1.f + expf(-gi));
      const float fv = 1.f / (1.f + expf(-gf));
      const float gv = tanhf(gg);
      creg = fmaf(fv, creg, iv * gv);
      const float hv = iv * tanhf(creg);  // o_t = i_t (faithful to source)
      // direct publish: [wg][b][c] flat idx == tid (b=tid>>2, hc=tid&3).
      // NO drain: pre-store memory is sentinel, early readers just retry.
      const uint64_t daddr =
          (uint64_t)(hbank + (size_t)(t + 1) * HSLICE + (size_t)wg * (BSZ * HS)) +
          (uint64_t)tid * 4u;
      asm volatile("global_store_dword %0, %1, off sc0 sc1"
                   :: "v"(daddr), "v"(hv)
                   : "memory");
      // recall-gate partial for step t+1: per owner wave, fixed butterfly.
      double p = wgt * (double)hv;
      p += __shfl_xor(p, 32, 64);
      p += __shfl_xor(p, 16, 64);
      p += __shfl_xor(p, 8, 64);
      p += __shfl_xor(p, 4, 64);
      p += __shfl_xor(p, 2, 64);
      p += __shfl_xor(p, 1, 64);
      if (lane == 0) {
        const uint64_t pa =
            (uint64_t)(gp + (size_t)(t + 1) * 128 + (size_t)((tid >> 6) * 64 + wg));
        asm volatile("global_store_dwordx2 %0, %1, off sc0 sc1"
                     :: "v"(pa), "v"(p)
                     : "memory");
      }
    }
    // ---- threads 160..255 (idle since C1-store): poll xw for t+1 into the
    // other xwL buffer. Overlaps owners' P-mix; loop-top B orders visibility.
    if (t + 1 < T_STEPS) { XW_POLL(t + 1) }
    // no barrier D: next step's poll-gather IS the sync
  }
#undef XW_POLL
}

// ------------------------------ Output -------------------------------------
__global__ void outK(const float* __restrict__ hbank, const float* __restrict__ W_out,
                     const float* __restrict__ b_out, float* __restrict__ out) {
  const int b = threadIdx.x;
  if (b < BSZ) {
    const float* h = hbank + (size_t)T_STEPS * HSLICE;  // [wg][b][c]
    float s = 0.f;
    for (int wg = 0; wg < KWG; ++wg) {
      const float4 hv = *(const float4*)&h[wg * (BSZ * HS) + b * HS];
      const float4 wv = *(const float4*)&W_out[wg * HS];
      s = fmaf(hv.x, wv.x, s); s = fmaf(hv.y, wv.y, s);
      s = fmaf(hv.z, wv.z, s); s = fmaf(hv.w, wv.w, s);
    }
    out[b] = s + b_out[0];
  }
}

// ------------------------------ Launch -------------------------------------
extern "C" void kernel_launch(void* const* d_in, const int* in_sizes, int n_in,
                              void* d_out, int out_size, void* d_ws, size_t ws_size,
                              hipStream_t stream) {
  const float* x      = (const float*)d_in[0];
  const float* W      = (const float*)d_in[1];
  const float* U      = (const float*)d_in[2];
  const float* P      = (const float*)d_in[3];
  const float* B_bias = (const float*)d_in[4];
  const float* W_r    = (const float*)d_in[5];
  const float* P_r    = (const float*)d_in[6];
  const float* U_r    = (const float*)d_in[7];
  const float* W_out  = (const float*)d_in[8];
  const float* b_out  = (const float*)d_in[9];

  char* ws = (char*)d_ws;
  float*    AXc   = (float*)ws;
  float*    hbank = (float*)(ws + AXC_BYTES);
  double*   gx    = (double*)(ws + AXC_BYTES + HB_BYTES);
  double*   gp    = (double*)(ws + AXC_BYTES + HB_BYTES + GX_BYTES);

  // Sentinel prefill (0xFF bytes -> all-ones dwords/qwords: never produced
  // by finite arithmetic): AXc + gx sentinel'd for producer/consumer
  // pipelining, then h0 = 0 in hbank slice 0.
  hipMemsetAsync(AXc, 0xFF, AXC_BYTES, stream);
  hipMemsetAsync(hbank, 0xFF, HB_BYTES, stream);
  hipMemsetAsync(gx, 0xFF, GX_BYTES, stream);
  hipMemsetAsync(gp, 0xFF, GP_BYTES, stream);
  hipMemsetAsync(hbank, 0, (size_t)HSLICE * sizeof(float), stream);

  fusedK<<<KWG + NWRK, 256, 0, stream>>>(x, W, W_r, U, P, B_bias, P_r, U_r,
                                         AXc, hbank, gx, gp);
  outK<<<1, 64, 0, stream>>>(hbank, W_out, b_out, (float*)d_out);
}